// Round 8
// baseline (549.741 us; speedup 1.0000x reference)
//
#include <hip/hip_runtime.h>
#include <stdint.h>

#define KCB 196560   // codebook rows
#define DIM 24       // embed dim
#define BB  2        // batch
#define ZEL 12288    // B*D*16*16
#define NRB 768      // row-blocks (768*256 = 196608 >= 196560)
#define RBS 256      // rows per score block
#define GRID 768     // persistent blocks = 3/CU (co-resident: 16.4KB LDS, VGPR<=170)
#define NFIN 48      // finalize/update blocks (one (b,d) plane each)
#define NCTR 64      // arrival counters per barrier
#define CSTR 64      // uint stride between counters (256B)

typedef __attribute__((ext_vector_type(8)))  __bf16 bf16x8;
typedef __attribute__((ext_vector_type(16))) float  f32x16;

__device__ const int TS_d[10] = {1, 2, 3, 4, 5, 6, 8, 10, 13, 16};

__device__ __forceinline__ unsigned long long pack_key(float sim, int idx) {
  unsigned u = __float_as_uint(sim);
  u = (u & 0x80000000u) ? ~u : (u | 0x80000000u);       // order-preserving float->u32
  return ((unsigned long long)u << 32) | (unsigned)(~(unsigned)idx); // smaller idx wins ties
}

// ---------- device-coherent (agent-scope) accessors: cross-block data only ----------
__device__ __forceinline__ void st_agent(float* p, float v) {
  __hip_atomic_store((unsigned*)p, __float_as_uint(v),
                     __ATOMIC_RELAXED, __HIP_MEMORY_SCOPE_AGENT);
}
__device__ __forceinline__ float ld_agent(const float* p) {
  return __uint_as_float(__hip_atomic_load((const unsigned*)p,
                         __ATOMIC_RELAXED, __HIP_MEMORY_SCOPE_AGENT));
}

// ---------- distributed fence-free barrier (round-6 proven; <=48 pollers only) ----------
__device__ __forceinline__ void bar_arrive(unsigned* ctr) {
  __syncthreads();                    // drains vmcnt: all prior stores acked
  if (threadIdx.x == 0)
    __hip_atomic_fetch_add(&ctr[(blockIdx.x & (NCTR - 1)) * CSTR], 1u,
                           __ATOMIC_RELAXED, __HIP_MEMORY_SCOPE_AGENT);
}
__device__ __forceinline__ void bar_wait(unsigned* ctr, unsigned NB) {
  if (threadIdx.x < 64) {
    while (true) {
      unsigned v = __hip_atomic_load(&ctr[threadIdx.x * CSTR],
                                     __ATOMIC_RELAXED, __HIP_MEMORY_SCOPE_AGENT);
      unsigned s = v;
#pragma unroll
      for (int d = 32; d; d >>= 1) s += __shfl_xor(s, d);
      if (s >= NB) break;
      __builtin_amdgcn_s_sleep(8);
    }
  }
  __syncthreads();
}
// ---- epoch flag: mass-wait path (1 word, 1 lane, long sleep - near-zero traffic) ----
__device__ __forceinline__ void flag_set(unsigned* flag, unsigned epoch) {
  __syncthreads();
  if (threadIdx.x == 0)
    __hip_atomic_store(flag, epoch, __ATOMIC_RELAXED, __HIP_MEMORY_SCOPE_AGENT);
}
__device__ __forceinline__ void flag_wait(unsigned* flag, unsigned epoch) {
  if (threadIdx.x == 0) {
    while (__hip_atomic_load(flag, __ATOMIC_RELAXED, __HIP_MEMORY_SCOPE_AGENT) < epoch)
      __builtin_amdgcn_s_sleep(32);
  }
  __syncthreads();
}

// ---------- prep: zero out+counters, cbprep, residual=z, t=1 downsample ----------
__global__ __launch_bounds__(256) void prep_kernel(const float* __restrict__ z,
    const float* __restrict__ cb, float* __restrict__ residual, float* __restrict__ out,
    float* __restrict__ rdown, ushort* __restrict__ ch, ushort* __restrict__ cl,
    unsigned* __restrict__ ctr, int outTotal) {
  __shared__ float plane[256];
  int tid = threadIdx.x;
  int e = blockIdx.x * 256 + tid;
  if (e < outTotal) out[e] = 0.0f;
  if (e < 32 * NCTR * CSTR) ctr[e] = 0u;
  if (e < KCB * 6) {                           // codebook hi/lo pack
    int row = e / 6, q = e - row * 6;
    float4 v = *(const float4*)(cb + (size_t)row * 24 + q * 4);
    float xs[4] = {v.x, v.y, v.z, v.w};
    unsigned h[4], l[4];
#pragma unroll
    for (int k = 0; k < 4; ++k) {
      unsigned bits = __float_as_uint(xs[k]);
      h[k] = bits >> 16;
      float hif = __uint_as_float(bits & 0xffff0000u);
      l[k] = __float_as_uint(xs[k] - hif) >> 16;   // exact in fp32
    }
    *(uint2*)(ch + (size_t)row * 24 + q * 4) = make_uint2(h[0] | (h[1] << 16), h[2] | (h[3] << 16));
    *(uint2*)(cl + (size_t)row * 24 + q * 4) = make_uint2(l[0] | (l[1] << 16), l[2] | (l[3] << 16));
  }
  if (blockIdx.x < 48) {                       // 48 blocks = 48 (b,d) planes
    float v = z[e];
    residual[e] = v;
    plane[tid] = v;
    __syncthreads();
    if (tid == 0) {                            // t=1: single token per plane
      int t = 1;
      float inv_scale = 16.0f / (float)t;
      float ks = inv_scale;
      float sf_h = (0.0f + 0.5f) * inv_scale - 0.5f;
      float sf_w = (0.0f + 0.5f) * inv_scale - 0.5f;
      float wh[16], ww[16];
      float sh = 0.f, sw = 0.f;
#pragma unroll
      for (int i = 0; i < 16; ++i) {
        float vh = fmaxf(0.f, 1.f - fabsf(sf_h - (float)i) / ks);
        wh[i] = vh; sh += vh;
        float vw = fmaxf(0.f, 1.f - fabsf(sf_w - (float)i) / ks);
        ww[i] = vw; sw += vw;
      }
#pragma unroll
      for (int i = 0; i < 16; ++i) { wh[i] /= sh; ww[i] /= sw; }
      float acc = 0.f;
      for (int ih = 0; ih < 16; ++ih) {
        float ra = 0.f;
#pragma unroll
        for (int iw = 0; iw < 16; ++iw) ra = fmaf(ww[iw], plane[ih * 16 + iw], ra);
        acc = fmaf(wh[ih], ra, acc);
      }
      int b = blockIdx.x / DIM, d = blockIdx.x - (blockIdx.x / DIM) * DIM;
      rdown[b * DIM + d] = acc;                // token b (n=1), normal store (boundary flush)
    }
  }
}

// ---------- score one (rb, token-tile): tokens from LDS, codebook cached ----------
// sim ~ (c_hi + c_lo).t_hi + c_hi.t_lo  (round-1 proven terms, eps=1e-3 semantics).
__device__ __forceinline__ void score_tile(int rb, int tbase, int T,
    const ushort* __restrict__ ch, const ushort* __restrict__ cl,
    const ushort* tkh, const ushort* tkl, float (*lmax)[4][32], float* blockmax) {
  const int tid = threadIdx.x, lane = tid & 63, wv = tid >> 6;
  const int col = lane & 31, g = lane >> 5;
  const int nrem = T - tbase;
  const int ntt = min(4, (nrem + 31) >> 5);
  const uint4 z4 = make_uint4(0, 0, 0, 0);

  bf16x8 bh[4][2], bl[4][2];
#pragma unroll
  for (int tt = 0; tt < 4; ++tt) {
    int lt = tt * 32 + col;                    // tile-local token
    bool tv = (tt < ntt) && (lt < nrem);
    uint4 h0 = tv ? *(const uint4*)(tkh + lt * 24 + g * 8) : z4;
    uint4 h1 = (tv && g == 0) ? *(const uint4*)(tkh + lt * 24 + 16) : z4;  // k16..23
    uint4 l0 = tv ? *(const uint4*)(tkl + lt * 24 + g * 8) : z4;
    uint4 l1 = (tv && g == 0) ? *(const uint4*)(tkl + lt * 24 + 16) : z4;
    bh[tt][0] = __builtin_bit_cast(bf16x8, h0);
    bh[tt][1] = __builtin_bit_cast(bf16x8, h1);
    bl[tt][0] = __builtin_bit_cast(bf16x8, l0);
    bl[tt][1] = __builtin_bit_cast(bf16x8, l1);
  }

  const f32x16 fzero = {};
  float runmax[4] = {-3.402823466e38f, -3.402823466e38f, -3.402823466e38f, -3.402823466e38f};
  const int rbase = rb * RBS + wv * 64;

#pragma unroll
  for (int rt = 0; rt < 2; ++rt) {
    int tilebase = rbase + rt * 32;
    if (tilebase >= KCB) continue;             // wave-uniform
    int row = tilebase + col;
    bool rv = row < KCB;
    const ushort* cr = ch + (size_t)row * 24;
    const ushort* dr = cl + (size_t)row * 24;
    uint4 a0 = rv ? *(const uint4*)(cr + g * 8) : z4;
    uint4 a1 = (rv && g == 0) ? *(const uint4*)(cr + 16) : z4;
    uint4 c0 = rv ? *(const uint4*)(dr + g * 8) : z4;
    uint4 c1 = (rv && g == 0) ? *(const uint4*)(dr + 16) : z4;
    bf16x8 ah0 = __builtin_bit_cast(bf16x8, a0);
    bf16x8 ah1 = __builtin_bit_cast(bf16x8, a1);
    bf16x8 al0 = __builtin_bit_cast(bf16x8, c0);
    bf16x8 al1 = __builtin_bit_cast(bf16x8, c1);
    int limit = KCB - tilebase;
    bool full = limit >= 32;
#pragma unroll
    for (int tt = 0; tt < 4; ++tt) {
      if (tt >= ntt) continue;
      f32x16 acc = __builtin_amdgcn_mfma_f32_32x32x16_bf16(ah0, bh[tt][0], fzero, 0, 0, 0);
      acc = __builtin_amdgcn_mfma_f32_32x32x16_bf16(ah1, bh[tt][1], acc, 0, 0, 0);
      acc = __builtin_amdgcn_mfma_f32_32x32x16_bf16(al0, bh[tt][0], acc, 0, 0, 0);
      acc = __builtin_amdgcn_mfma_f32_32x32x16_bf16(al1, bh[tt][1], acc, 0, 0, 0);
      acc = __builtin_amdgcn_mfma_f32_32x32x16_bf16(ah0, bl[tt][0], acc, 0, 0, 0);
      acc = __builtin_amdgcn_mfma_f32_32x32x16_bf16(ah1, bl[tt][1], acc, 0, 0, 0);
      float m;
      if (full) {
        float m01 = fmaxf(acc[0], acc[1]),  m23 = fmaxf(acc[2], acc[3]);
        float m45 = fmaxf(acc[4], acc[5]),  m67 = fmaxf(acc[6], acc[7]);
        float m89 = fmaxf(acc[8], acc[9]),  mab = fmaxf(acc[10], acc[11]);
        float mcd = fmaxf(acc[12], acc[13]), mef = fmaxf(acc[14], acc[15]);
        m = fmaxf(fmaxf(fmaxf(m01, m23), fmaxf(m45, m67)),
                  fmaxf(fmaxf(m89, mab), fmaxf(mcd, mef)));
      } else {
        m = -3.402823466e38f;                  // mask rows >= KCB
#pragma unroll
        for (int r = 0; r < 16; ++r) {
          int rowid = (r & 3) + 8 * (r >> 2) + 4 * g;
          if (rowid < limit) m = fmaxf(m, acc[r]);
        }
      }
      runmax[tt] = fmaxf(runmax[tt], m);
    }
  }

#pragma unroll
  for (int tt = 0; tt < 4; ++tt) {
    float v = fmaxf(runmax[tt], __shfl_xor(runmax[tt], 32));
    if (lane < 32) lmax[wv][tt][col] = v;
  }
  __syncthreads();
  if (tid < 128) {
    int tt = tid >> 5, c = tid & 31;
    if (tt < ntt) {
      float m = fmaxf(fmaxf(lmax[0][tt][c], lmax[1][tt][c]),
                      fmaxf(lmax[2][tt][c], lmax[3][tt][c]));
      int token = tbase + tt * 32 + c;
      if (token < T) st_agent(&blockmax[token * NRB + rb], m);
    }
  }
}

// ---------- finalize one token (one wave): prune + exact rescan + zq ----------
__device__ __forceinline__ void finalize_token(int tok, const float* __restrict__ cb,
    const float* rdown, const float* __restrict__ blockmax, float* __restrict__ zq_ws,
    float* __restrict__ out, int idxBase) {
  int lane = threadIdx.x & 63;
  float x = (lane < DIM) ? ld_agent(&rdown[tok * DIM + lane]) : 0.f;
  float av[DIM];
#pragma unroll
  for (int k = 0; k < DIM; ++k)
    av[k] = __uint_as_float(__builtin_amdgcn_readlane(__float_as_uint(x), k));
  float ss = 0.f;
#pragma unroll
  for (int k = 0; k < DIM; ++k) ss = fmaf(av[k], av[k], ss);
  // eps = 1e-3*|a| >= 5x split-bf16 error bound: true argmax block provably kept
  float eps = 1e-3f * sqrtf(ss) + 1e-30f;

  const float* bmrow = blockmax + (size_t)tok * NRB;
  float bv[12];
#pragma unroll
  for (int i = 0; i < 12; ++i) bv[i] = ld_agent(&bmrow[lane + 64 * i]);  // 768 = 64*12
  float M = bv[0];
#pragma unroll
  for (int i = 1; i < 12; ++i) M = fmaxf(M, bv[i]);
#pragma unroll
  for (int d = 32; d; d >>= 1) M = fmaxf(M, __shfl_xor(M, d));
  float thr = M - eps;

  unsigned long long bk = 0ull;
#pragma unroll
  for (int i = 0; i < 12; ++i) {
    unsigned long long mask = __ballot(bv[i] >= thr);
    while (mask) {                              // wave-uniform, expected ~1 iter total
      int l = __ffsll((unsigned long long)mask) - 1;
      mask &= mask - 1;
      int rowb = (l + 64 * i) * RBS;
      for (int r8 = 0; r8 < 4; ++r8) {          // RBS=256 -> 4 x 64 rows
        int row = rowb + r8 * 64 + lane;
        if (row < KCB) {
          const float* cv = cb + (size_t)row * DIM;
          float acc = 0.f;
#pragma unroll
          for (int k = 0; k < DIM; ++k) acc = fmaf(av[k], cv[k], acc);  // exact chain
          unsigned long long key = pack_key(acc, row);
          if (key > bk) bk = key;               // rows ascend per lane -> lowest idx kept
        }
      }
    }
  }
#pragma unroll
  for (int d = 32; d; d >>= 1) {
    unsigned long long o = __shfl_xor(bk, d);
    if (o > bk) bk = o;
  }
  int idx = (int)(~(unsigned)bk);
  const float* cv = cb + (long long)idx * DIM;
  float xv = (lane < DIM) ? cv[lane] : 0.f;
  float v[DIM];
#pragma unroll
  for (int k = 0; k < DIM; ++k)
    v[k] = __uint_as_float(__builtin_amdgcn_readlane(__float_as_uint(xv), k));
  float s2 = 0.f;
#pragma unroll
  for (int k = 0; k < DIM; ++k) s2 = fmaf(v[k], v[k], s2);
  float nrm = sqrtf(s2);
  if (lane < DIM) st_agent(&zq_ws[tok * DIM + lane], xv / nrm);
  if (lane == 0) out[idxBase + tok] = (float)idx;
}

// ---------- update plane (runtime t): upsample, z_hat/residual, next downpack ----------
__device__ __forceinline__ void update_plane_rt(int tsz, int tnext,
    const float* __restrict__ zq_ws, float* residual, float* __restrict__ out,
    float* rdown, float* ldsZ, float* plane) {
  int N = tsz * tsz;
  int tid = threadIdx.x;
  int p = blockIdx.x;
  int b = p / DIM, d = p - b * DIM;
  for (int sp = tid; sp < N; sp += 256) ldsZ[sp] = ld_agent(&zq_ws[(b * N + sp) * DIM + d]);
  __syncthreads();
  int e = p * 256 + tid;
  int w = e & 15, h = (e >> 4) & 15;
  float inv_scale = (float)tsz / 16.0f;
  float sf_h = ((float)h + 0.5f) * inv_scale - 0.5f;
  float sf_w = ((float)w + 0.5f) * inv_scale - 0.5f;
  float wh[16], ww[16];
  float sh = 0.f, sw = 0.f;
  for (int j = 0; j < tsz; ++j) {
    float vh = fmaxf(0.f, 1.f - fabsf(sf_h - (float)j));
    wh[j] = vh; sh += vh;
    float vw = fmaxf(0.f, 1.f - fabsf(sf_w - (float)j));
    ww[j] = vw; sw += vw;
  }
  for (int j = 0; j < tsz; ++j) { wh[j] /= sh; ww[j] /= sw; }
  float acc = 0.f;
  for (int thh = 0; thh < tsz; ++thh) {
    float ra = 0.f;
    for (int tw = 0; tw < tsz; ++tw) ra = fmaf(ww[tw], ldsZ[thh * tsz + tw], ra);
    acc = fmaf(wh[thh], ra, acc);
  }
  out[e] += acc;                               // same block p every scale: cached ok
  float rn = residual[e] - acc;
  residual[e] = rn;

  if (tnext > 0) {                             // next-scale downsample, in-LDS
    plane[tid] = rn;
    __syncthreads();
    int n2 = tnext * tnext;
    for (int sp = tid; sp < n2; sp += 256) {
      int oh = sp / tnext, ow = sp - oh * tnext;
      float inv2 = 16.0f / (float)tnext;
      float ks = inv2;
      float s_h = ((float)oh + 0.5f) * inv2 - 0.5f;
      float s_w = ((float)ow + 0.5f) * inv2 - 0.5f;
      float wh2[16], ww2[16];
      float sh2 = 0.f, sw2 = 0.f;
      for (int i = 0; i < 16; ++i) {
        float vh = fmaxf(0.f, 1.f - fabsf(s_h - (float)i) / ks);
        wh2[i] = vh; sh2 += vh;
        float vw = fmaxf(0.f, 1.f - fabsf(s_w - (float)i) / ks);
        ww2[i] = vw; sw2 += vw;
      }
      for (int i = 0; i < 16; ++i) { wh2[i] /= sh2; ww2[i] /= sw2; }
      float acc2 = 0.f;
      for (int ih = 0; ih < 16; ++ih) {
        float ra = 0.f;
        for (int iw = 0; iw < 16; ++iw) ra = fmaf(ww2[iw], plane[ih * 16 + iw], ra);
        acc2 = fmaf(wh2[ih], ra, acc2);
      }
      st_agent(&rdown[(b * n2 + sp) * DIM + d], acc2);  // cross-block next-scale read
    }
  }
}

// ---------- single persistent kernel: all 10 scales, codebook L2-warm after scale 1 ----------
__global__ __launch_bounds__(256, 3) void fused_kernel(
    const ushort* __restrict__ ch, const ushort* __restrict__ cl,
    const float* __restrict__ cb,
    float* rdown, float* blockmax, float* zq_ws,
    float* residual, float* out, unsigned* ctr, unsigned* flag) {
  __shared__ __align__(16) ushort tkh[128 * DIM];   // 6 KB token-tile hi
  __shared__ __align__(16) ushort tkl[128 * DIM];   // 6 KB token-tile lo
  __shared__ float lmax[4][4][32];                  // 2 KB
  __shared__ float ldsZ[256];
  __shared__ float plane[256];

  const int tid = threadIdx.x;
  const int bid = blockIdx.x;                       // = rb (stable L2/XCD mapping)
  int prefix = 0;
  for (int s = 0; s < 10; ++s) {
    const int t = TS_d[s];
    const int n = t * t, T = BB * n;
    const int ntb = (T + 127) >> 7;
    unsigned* cA = ctr + (size_t)(3 * s + 0) * NCTR * CSTR;
    unsigned* cB = ctr + (size_t)(3 * s + 1) * NCTR * CSTR;
    unsigned* cC = ctr + (size_t)(3 * s + 2) * NCTR * CSTR;

    // phase A: stage token tile(s) from agent-coherent rdown -> LDS, then score
    for (int tb = 0; tb < ntb; ++tb) {
      int tbase = tb * 128;
      int ntok = min(128, T - tbase);
      __syncthreads();
      for (int i = tid; i < ntok * DIM; i += 256) {
        float v = ld_agent(&rdown[tbase * DIM + i]);
        unsigned bits = __float_as_uint(v);
        tkh[i] = (ushort)(bits >> 16);
        float hif = __uint_as_float(bits & 0xffff0000u);
        tkl[i] = (ushort)(__float_as_uint(v - hif) >> 16);   // exact in fp32
      }
      __syncthreads();
      score_tile(bid, tbase, T, ch, cl, tkh, tkl, lmax, blockmax);
    }
    bar_arrive(cA);

    if (bid < NFIN) {
      // phase B: finalize (48 blocks x 4 waves = 192 waves over T tokens)
      bar_wait(cA, GRID);                           // <=48 pollers: cheap
      int wv = tid >> 6;
      for (int tok = bid * 4 + wv; tok < T; tok += 4 * NFIN)
        finalize_token(tok, cb, rdown, blockmax, zq_ws, out, ZEL + BB * prefix);
      bar_arrive(cB);
      bar_wait(cB, NFIN);
      // phase C: update plane bid (+ next-scale downpack)
      update_plane_rt(t, (s < 9) ? TS_d[s + 1] : 0, zq_ws, residual, out, rdown, ldsZ, plane);
      bar_arrive(cC);
      if (bid == 0) {                               // sole aggregator -> release flag
        bar_wait(cC, NFIN);
        flag_set(flag, (unsigned)(s + 1));
      }
    }
    // mass wait: ONE word, ONE lane, long sleep (no 64-line poll storms)
    flag_wait(flag, (unsigned)(s + 1));
    prefix += n;
  }
}

// ---------- host: 2 dispatches total ----------
extern "C" void kernel_launch(void* const* d_in, const int* in_sizes, int n_in,
                              void* d_out, int out_size, void* d_ws, size_t ws_size,
                              hipStream_t stream) {
  const float* z  = (const float*)d_in[0];
  const float* cb = (const float*)d_in[1];
  float* out = (float*)d_out;
  float* residual = (float*)d_ws;                          // 12288 f
  float* rdown = residual + ZEL;                           // 12288 f (agent-coherent)
  float* blockmax = rdown + ZEL;                           // 512*768 f (agent-coherent)
  float* zq_ws = blockmax + 512 * NRB;                     // 12288 f (agent-coherent)
  unsigned* ctr = (unsigned*)(zq_ws + ZEL);                // 32 x NCTR*CSTR u32 (slot 31 unused)
  unsigned* flag = ctr + (size_t)30 * NCTR * CSTR;         // epoch flag (zeroed by prep)
  ushort* ch = (ushort*)(ctr + 32 * NCTR * CSTR);          // 196560*24 u16 codebook hi
  ushort* cl = ch + (size_t)KCB * DIM;                     // 196560*24 u16 codebook lo

  prep_kernel<<<(KCB * 6 + 255) / 256, 256, 0, stream>>>(z, cb, residual, out, rdown,
                                                         ch, cl, ctr, out_size);
  fused_kernel<<<GRID, 256, 0, stream>>>(ch, cl, cb, rdown, blockmax, zq_ws,
                                         residual, out, ctr, flag);
}

// Round 9
// 429.103 us; speedup vs baseline: 1.2811x; 1.2811x over previous
//
#include <hip/hip_runtime.h>
#include <stdint.h>

#define KCB 196560   // codebook rows
#define DIM 24       // embed dim
#define BB  2        // batch
#define ZEL 12288    // B*D*16*16
#define NRB 768      // row-blocks (768*256 = 196608 >= 196560)
#define RBS 256      // rows per score block
#define GRID 768     // persistent blocks; each owns one 256-row codebook slice in regs
#define NFIN 48      // finalize/update blocks (one (b,d) plane each)
#define TMAX 512     // max tokens per scale
#define NCTR 64      // arrival counters per barrier
#define CSTR 64      // uint stride between counters (256B)

typedef __attribute__((ext_vector_type(8)))  __bf16 bf16x8;
typedef __attribute__((ext_vector_type(16))) float  f32x16;

__device__ const int TS_d[10] = {1, 2, 3, 4, 5, 6, 8, 10, 13, 16};

__device__ __forceinline__ unsigned long long pack_key(float sim, int idx) {
  unsigned u = __float_as_uint(sim);
  u = (u & 0x80000000u) ? ~u : (u | 0x80000000u);       // order-preserving float->u32
  return ((unsigned long long)u << 32) | (unsigned)(~(unsigned)idx); // smaller idx wins ties
}

// ---------- agent-scope (coherence-point) accessors: producers of cross-block data ----------
__device__ __forceinline__ void st_agent(float* p, float v) {
  __hip_atomic_store((unsigned*)p, __float_as_uint(v),
                     __ATOMIC_RELAXED, __HIP_MEMORY_SCOPE_AGENT);
}

// ---------- distributed fence-free barrier (rounds 6-8 proven) ----------
__device__ __forceinline__ void bar_arrive(unsigned* ctr) {
  __syncthreads();                    // drains vmcnt: all prior stores acked at coherence point
  if (threadIdx.x == 0)
    __hip_atomic_fetch_add(&ctr[(blockIdx.x & (NCTR - 1)) * CSTR], 1u,
                           __ATOMIC_RELAXED, __HIP_MEMORY_SCOPE_AGENT);
}
__device__ __forceinline__ void bar_wait(unsigned* ctr, unsigned NB) {
  if (threadIdx.x < 64) {
    while (true) {
      unsigned v = __hip_atomic_load(&ctr[threadIdx.x * CSTR],
                                     __ATOMIC_RELAXED, __HIP_MEMORY_SCOPE_AGENT);
      unsigned s = v;
#pragma unroll
      for (int d = 32; d; d >>= 1) s += __shfl_xor(s, d);
      if (s >= NB) break;
      __builtin_amdgcn_s_sleep(8);
    }
  }
  __syncthreads();
}
__device__ __forceinline__ void flag_set(unsigned* flag, unsigned epoch) {
  __syncthreads();
  if (threadIdx.x == 0)
    __hip_atomic_store(flag, epoch, __ATOMIC_RELAXED, __HIP_MEMORY_SCOPE_AGENT);
}
__device__ __forceinline__ void flag_wait(unsigned* flag, unsigned epoch) {
  if (threadIdx.x == 0) {
    while (__hip_atomic_load(flag, __ATOMIC_RELAXED, __HIP_MEMORY_SCOPE_AGENT) < epoch)
      __builtin_amdgcn_s_sleep(32);
  }
  __syncthreads();
}

// ---------- split-bf16 conversion helpers (bit-identical to rounds 1-8) ----------
__device__ __forceinline__ void load8(const float* p, float* xs) {
  float4 a = *(const float4*)p;
  float4 b = *(const float4*)(p + 4);
  xs[0]=a.x; xs[1]=a.y; xs[2]=a.z; xs[3]=a.w;
  xs[4]=b.x; xs[5]=b.y; xs[6]=b.z; xs[7]=b.w;
}
__device__ __forceinline__ void cvt_hi_lo(const float* xs, uint4& hw, uint4& lw) {
  unsigned h[8], l[8];
#pragma unroll
  for (int j = 0; j < 8; ++j) {
    unsigned b = __float_as_uint(xs[j]);
    h[j] = b >> 16;
    float hif = __uint_as_float(b & 0xffff0000u);
    l[j] = __float_as_uint(xs[j] - hif) >> 16;   // exact in fp32
  }
  hw = make_uint4(h[0] | (h[1] << 16), h[2] | (h[3] << 16),
                  h[4] | (h[5] << 16), h[6] | (h[7] << 16));
  lw = make_uint4(l[0] | (l[1] << 16), l[2] | (l[3] << 16),
                  l[4] | (l[5] << 16), l[6] | (l[7] << 16));
}

// ---------- prep: zero out + counters, residual=z, t=1 downsample ----------
__global__ __launch_bounds__(256) void prep_kernel(const float* __restrict__ z,
    float* __restrict__ residual, float* __restrict__ out, float* __restrict__ rdown0,
    unsigned* __restrict__ ctr, int outTotal) {
  __shared__ float plane[256];
  int tid = threadIdx.x;
  int e = blockIdx.x * 256 + tid;
  if (e < outTotal) out[e] = 0.0f;
  if (e < 32 * NCTR * CSTR) ctr[e] = 0u;
  if (blockIdx.x < 48) {                       // 48 blocks = 48 (b,d) planes
    float v = z[e];
    residual[e] = v;
    plane[tid] = v;
    __syncthreads();
    if (tid == 0) {                            // t=1: single token per plane
      float inv_scale = 16.0f;
      float ks = inv_scale;
      float sf_h = 0.5f * inv_scale - 0.5f;
      float sf_w = 0.5f * inv_scale - 0.5f;
      float wh[16], ww[16];
      float sh = 0.f, sw = 0.f;
#pragma unroll
      for (int i = 0; i < 16; ++i) {
        float vh = fmaxf(0.f, 1.f - fabsf(sf_h - (float)i) / ks);
        wh[i] = vh; sh += vh;
        float vw = fmaxf(0.f, 1.f - fabsf(sf_w - (float)i) / ks);
        ww[i] = vw; sw += vw;
      }
#pragma unroll
      for (int i = 0; i < 16; ++i) { wh[i] /= sh; ww[i] /= sw; }
      float acc = 0.f;
      for (int ih = 0; ih < 16; ++ih) {
        float ra = 0.f;
#pragma unroll
        for (int iw = 0; iw < 16; ++iw) ra = fmaf(ww[iw], plane[ih * 16 + iw], ra);
        acc = fmaf(wh[ih], ra, acc);
      }
      int b = blockIdx.x / DIM, d = blockIdx.x - (blockIdx.x / DIM) * DIM;
      rdown0[b * DIM + d] = acc;               // normal store; boundary flush -> fresh
    }
  }
}

// ---------- finalize one token (one wave): prune + exact rescan + zq ----------
__device__ __forceinline__ void finalize_token(int tok, const float* __restrict__ cb,
    const float* __restrict__ rdown, const float* __restrict__ bm,
    float* __restrict__ zq, float* __restrict__ out, int idxBase) {
  int lane = threadIdx.x & 63;
  float x = (lane < DIM) ? rdown[tok * DIM + lane] : 0.f;   // cached (staged this scale)
  float av[DIM];
#pragma unroll
  for (int k = 0; k < DIM; ++k)
    av[k] = __uint_as_float(__builtin_amdgcn_readlane(__float_as_uint(x), k));
  float ss = 0.f;
#pragma unroll
  for (int k = 0; k < DIM; ++k) ss = fmaf(av[k], av[k], ss);
  // eps = 1e-3*|a| >= 5x split-bf16 error bound: true argmax block provably kept
  float eps = 1e-3f * sqrtf(ss) + 1e-30f;

  float bv[12];
#pragma unroll
  for (int i = 0; i < 12; ++i)
    bv[i] = bm[(size_t)(lane + 64 * i) * TMAX + tok];        // cached, virgin this scale
  float M = bv[0];
#pragma unroll
  for (int i = 1; i < 12; ++i) M = fmaxf(M, bv[i]);
#pragma unroll
  for (int d = 32; d; d >>= 1) M = fmaxf(M, __shfl_xor(M, d));
  float thr = M - eps;

  unsigned long long bk = 0ull;
#pragma unroll
  for (int i = 0; i < 12; ++i) {
    unsigned long long mask = __ballot(bv[i] >= thr);
    while (mask) {                              // wave-uniform, expected ~1 iter total
      int l = __ffsll((unsigned long long)mask) - 1;
      mask &= mask - 1;
      int rowb = (l + 64 * i) * RBS;
      for (int r8 = 0; r8 < 4; ++r8) {          // RBS=256 -> 4 x 64 rows
        int row = rowb + r8 * 64 + lane;
        if (row < KCB) {
          const float* cv = cb + (size_t)row * DIM;
          float acc = 0.f;
#pragma unroll
          for (int k = 0; k < DIM; ++k) acc = fmaf(av[k], cv[k], acc);  // exact chain
          unsigned long long key = pack_key(acc, row);
          if (key > bk) bk = key;               // rows ascend per lane -> lowest idx kept
        }
      }
    }
  }
#pragma unroll
  for (int d = 32; d; d >>= 1) {
    unsigned long long o = __shfl_xor(bk, d);
    if (o > bk) bk = o;
  }
  int idx = (int)(~(unsigned)bk);
  const float* cv = cb + (long long)idx * DIM;
  float xv = (lane < DIM) ? cv[lane] : 0.f;
  float v[DIM];
#pragma unroll
  for (int k = 0; k < DIM; ++k)
    v[k] = __uint_as_float(__builtin_amdgcn_readlane(__float_as_uint(xv), k));
  float s2 = 0.f;
#pragma unroll
  for (int k = 0; k < DIM; ++k) s2 = fmaf(v[k], v[k], s2);
  float nrm = sqrtf(s2);
  if (lane < DIM) st_agent(&zq[tok * DIM + lane], xv / nrm);  // cross-block producer
  if (lane == 0) out[idxBase + tok] = (float)idx;
}

// ---------- update plane: upsample, z_hat/residual, next-scale downsample ----------
__device__ __forceinline__ void update_plane_rt(int tsz, int tnext,
    const float* __restrict__ zq, float* residual, float* __restrict__ out,
    float* rdown_next, float* ldsZ, float* plane) {
  int N = tsz * tsz;
  int tid = threadIdx.x;
  int p = blockIdx.x;
  int b = p / DIM, d = p - b * DIM;
  for (int sp = tid; sp < N; sp += 256) ldsZ[sp] = zq[(b * N + sp) * DIM + d];  // cached, virgin
  __syncthreads();
  int e = p * 256 + tid;
  int w = e & 15, h = (e >> 4) & 15;
  float inv_scale = (float)tsz / 16.0f;
  float sf_h = ((float)h + 0.5f) * inv_scale - 0.5f;
  float sf_w = ((float)w + 0.5f) * inv_scale - 0.5f;
  float wh[16], ww[16];
  float sh = 0.f, sw = 0.f;
  for (int j = 0; j < tsz; ++j) {
    float vh = fmaxf(0.f, 1.f - fabsf(sf_h - (float)j));
    wh[j] = vh; sh += vh;
    float vw = fmaxf(0.f, 1.f - fabsf(sf_w - (float)j));
    ww[j] = vw; sw += vw;
  }
  for (int j = 0; j < tsz; ++j) { wh[j] /= sh; ww[j] /= sw; }
  float acc = 0.f;
  for (int thh = 0; thh < tsz; ++thh) {
    float ra = 0.f;
    for (int tw = 0; tw < tsz; ++tw) ra = fmaf(ww[tw], ldsZ[thh * tsz + tw], ra);
    acc = fmaf(wh[thh], ra, acc);
  }
  out[e] += acc;                               // block-private lines: cached rd/wr
  float rn = residual[e] - acc;
  residual[e] = rn;

  if (tnext > 0) {                             // next-scale downsample, in-LDS
    plane[tid] = rn;
    __syncthreads();
    int n2 = tnext * tnext;
    for (int sp = tid; sp < n2; sp += 256) {
      int oh = sp / tnext, ow = sp - oh * tnext;
      float inv2 = 16.0f / (float)tnext;
      float ks = inv2;
      float s_h = ((float)oh + 0.5f) * inv2 - 0.5f;
      float s_w = ((float)ow + 0.5f) * inv2 - 0.5f;
      float wh2[16], ww2[16];
      float sh2 = 0.f, sw2 = 0.f;
      for (int i = 0; i < 16; ++i) {
        float vh = fmaxf(0.f, 1.f - fabsf(s_h - (float)i) / ks);
        wh2[i] = vh; sh2 += vh;
        float vw = fmaxf(0.f, 1.f - fabsf(s_w - (float)i) / ks);
        ww2[i] = vw; sw2 += vw;
      }
      for (int i = 0; i < 16; ++i) { wh2[i] /= sh2; ww2[i] /= sw2; }
      float acc2 = 0.f;
      for (int ih = 0; ih < 16; ++ih) {
        float ra = 0.f;
        for (int iw = 0; iw < 16; ++iw) ra = fmaf(ww2[iw], plane[ih * 16 + iw], ra);
        acc2 = fmaf(wh2[ih], ra, acc2);
      }
      st_agent(&rdown_next[(b * n2 + sp) * DIM + d], acc2);  // cross-block producer
    }
  }
}

// ---------- single persistent kernel: codebook fragments live in REGISTERS ----------
__global__ __launch_bounds__(256, 3) void fused_kernel(
    const float* __restrict__ cb,
    float* rdown_s, float* blockmax_s, float* zq_s,
    float* residual, float* out, unsigned* ctr, unsigned* flag) {
  __shared__ __align__(16) ushort th_lds[TMAX * DIM];   // 24 KB token hi (whole scale)
  __shared__ __align__(16) ushort tl_lds[TMAX * DIM];   // 24 KB token lo
  __shared__ float lmax[4][4][32];                      // 2 KB
  __shared__ float ldsZ[256];
  __shared__ float plane[256];

  const int tid = threadIdx.x, lane = tid & 63, wv = tid >> 6;
  const int col = lane & 31, g = lane >> 5;
  const int bid = blockIdx.x;
  const uint4 z4 = make_uint4(0, 0, 0, 0);

  // ---- codebook fragments -> registers, ONCE (cached fp32 loads, hi/lo split) ----
  bf16x8 ah[2][2], al[2][2];   // [rt][khalf]
  int limit_rt[2];
#pragma unroll
  for (int rt = 0; rt < 2; ++rt) {
    int tilebase = bid * RBS + wv * 64 + rt * 32;
    limit_rt[rt] = KCB - tilebase;             // may be <=0 for the tail waves
    int row = tilebase + col;
    bool rv = (tilebase < KCB) && (row < KCB);
    uint4 h0 = z4, l0 = z4, h1 = z4, l1 = z4;
    if (rv) { float xs[8]; load8(cb + (size_t)row * DIM + g * 8, xs); cvt_hi_lo(xs, h0, l0); }
    if (rv && g == 0) { float xs[8]; load8(cb + (size_t)row * DIM + 16, xs); cvt_hi_lo(xs, h1, l1); }
    ah[rt][0] = __builtin_bit_cast(bf16x8, h0);
    ah[rt][1] = __builtin_bit_cast(bf16x8, h1);
    al[rt][0] = __builtin_bit_cast(bf16x8, l0);
    al[rt][1] = __builtin_bit_cast(bf16x8, l1);
  }
  const f32x16 fzero = {};

  int prefix = 0;
  for (int s = 0; s < 10; ++s) {
    const int t = TS_d[s];
    const int n = t * t, T = BB * n;
    const int ntb = (T + 127) >> 7;
    float* rdown = rdown_s + (size_t)s * TMAX * DIM;
    float* bm    = blockmax_s + (size_t)s * NRB * TMAX;
    float* zq    = zq_s + (size_t)s * TMAX * DIM;
    unsigned* cA = ctr + (size_t)(3 * s + 0) * NCTR * CSTR;
    unsigned* cB = ctr + (size_t)(3 * s + 1) * NCTR * CSTR;
    unsigned* cC = ctr + (size_t)(3 * s + 2) * NCTR * CSTR;

    // ---- stage whole scale's tokens -> LDS packed (CACHED loads, virgin addresses) ----
    __syncthreads();
    for (int i = tid; i < T * DIM; i += 256) {
      float v = rdown[i];
      unsigned bits = __float_as_uint(v);
      th_lds[i] = (ushort)(bits >> 16);
      float hif = __uint_as_float(bits & 0xffff0000u);
      tl_lds[i] = (ushort)(__float_as_uint(v - hif) >> 16);   // exact in fp32
    }
    __syncthreads();

    // ---- score all token tiles against this block's register-resident codebook ----
    for (int tb = 0; tb < ntb; ++tb) {
      int tbase = tb * 128;
      int nrem = T - tbase;
      int ntt = min(4, (nrem + 31) >> 5);
      bf16x8 bh[4][2], bl[4][2];
#pragma unroll
      for (int tt = 0; tt < 4; ++tt) {
        int lt = tbase + tt * 32 + col;
        bool tv = (tt < ntt) && (lt < T);
        uint4 h0 = tv ? *(const uint4*)&th_lds[lt * DIM + g * 8] : z4;
        uint4 h1 = (tv && g == 0) ? *(const uint4*)&th_lds[lt * DIM + 16] : z4;
        uint4 l0 = tv ? *(const uint4*)&tl_lds[lt * DIM + g * 8] : z4;
        uint4 l1 = (tv && g == 0) ? *(const uint4*)&tl_lds[lt * DIM + 16] : z4;
        bh[tt][0] = __builtin_bit_cast(bf16x8, h0);
        bh[tt][1] = __builtin_bit_cast(bf16x8, h1);
        bl[tt][0] = __builtin_bit_cast(bf16x8, l0);
        bl[tt][1] = __builtin_bit_cast(bf16x8, l1);
      }
      float runmax[4] = {-3.402823466e38f, -3.402823466e38f,
                         -3.402823466e38f, -3.402823466e38f};
#pragma unroll
      for (int rt = 0; rt < 2; ++rt) {
        int limit = limit_rt[rt];
        if (limit <= 0) continue;              // wave-uniform
        bool full = limit >= 32;
#pragma unroll
        for (int tt = 0; tt < 4; ++tt) {
          if (tt >= ntt) continue;
          f32x16 acc = __builtin_amdgcn_mfma_f32_32x32x16_bf16(ah[rt][0], bh[tt][0], fzero, 0, 0, 0);
          acc = __builtin_amdgcn_mfma_f32_32x32x16_bf16(ah[rt][1], bh[tt][1], acc, 0, 0, 0);
          acc = __builtin_amdgcn_mfma_f32_32x32x16_bf16(al[rt][0], bh[tt][0], acc, 0, 0, 0);
          acc = __builtin_amdgcn_mfma_f32_32x32x16_bf16(al[rt][1], bh[tt][1], acc, 0, 0, 0);
          acc = __builtin_amdgcn_mfma_f32_32x32x16_bf16(ah[rt][0], bl[tt][0], acc, 0, 0, 0);
          acc = __builtin_amdgcn_mfma_f32_32x32x16_bf16(ah[rt][1], bl[tt][1], acc, 0, 0, 0);
          float m;
          if (full) {
            float m01 = fmaxf(acc[0], acc[1]),  m23 = fmaxf(acc[2], acc[3]);
            float m45 = fmaxf(acc[4], acc[5]),  m67 = fmaxf(acc[6], acc[7]);
            float m89 = fmaxf(acc[8], acc[9]),  mab = fmaxf(acc[10], acc[11]);
            float mcd = fmaxf(acc[12], acc[13]), mef = fmaxf(acc[14], acc[15]);
            m = fmaxf(fmaxf(fmaxf(m01, m23), fmaxf(m45, m67)),
                      fmaxf(fmaxf(m89, mab), fmaxf(mcd, mef)));
          } else {
            m = -3.402823466e38f;              // mask rows >= KCB
#pragma unroll
            for (int r = 0; r < 16; ++r) {
              int rowid = (r & 3) + 8 * (r >> 2) + 4 * g;
              if (rowid < limit) m = fmaxf(m, acc[r]);
            }
          }
          runmax[tt] = fmaxf(runmax[tt], m);
        }
      }
#pragma unroll
      for (int tt = 0; tt < 4; ++tt) {
        float v = fmaxf(runmax[tt], __shfl_xor(runmax[tt], 32));
        if (lane < 32) lmax[wv][tt][col] = v;
      }
      __syncthreads();
      if (tid < 128) {
        int tt = tid >> 5, c = tid & 31;
        if (tt < ntt) {
          float m = fmaxf(fmaxf(lmax[0][tt][c], lmax[1][tt][c]),
                          fmaxf(lmax[2][tt][c], lmax[3][tt][c]));
          int token = tbase + tt * 32 + c;
          if (token < T)
            st_agent(&bm[(size_t)bid * TMAX + token], m);   // COALESCED [rb][tok] write
        }
      }
      __syncthreads();                         // lmax WAR before next tile
    }
    bar_arrive(cA);

    if (bid < NFIN) {
      // phase B: finalize over contiguous token chunk (line reuse on bm columns)
      bar_wait(cA, GRID);
      asm volatile("" ::: "memory");
      int chunk = (T + NFIN - 1) / NFIN;
      int tbeg = bid * chunk, tend = min(T, tbeg + chunk);
      for (int tok = tbeg + (tid >> 6); tok < tend; tok += 4)
        finalize_token(tok, cb, rdown, bm, zq, out, ZEL + BB * prefix);
      bar_arrive(cB);
      bar_wait(cB, NFIN);
      asm volatile("" ::: "memory");
      // phase C: update plane bid (+ next-scale downsample into rdown_s[s+1])
      update_plane_rt(t, (s < 9) ? TS_d[s + 1] : 0, zq, residual, out,
                      rdown_s + (size_t)(s + 1) * TMAX * DIM, ldsZ, plane);
      bar_arrive(cC);
      if (bid == 0) {                          // sole aggregator -> release flag
        bar_wait(cC, NFIN);
        flag_set(flag, (unsigned)(s + 1));
      }
    }
    flag_wait(flag, (unsigned)(s + 1));
    asm volatile("" ::: "memory");
    prefix += n;
  }
}

// ---------- host: 2 dispatches total ----------
extern "C" void kernel_launch(void* const* d_in, const int* in_sizes, int n_in,
                              void* d_out, int out_size, void* d_ws, size_t ws_size,
                              hipStream_t stream) {
  const float* z  = (const float*)d_in[0];
  const float* cb = (const float*)d_in[1];
  float* out = (float*)d_out;
  float* residual = (float*)d_ws;                          // 12288 f
  float* rdown_s = residual + ZEL;                         // 11 x TMAX*DIM f (s+1 write ok)
  float* zq_s = rdown_s + (size_t)11 * TMAX * DIM;         // 10 x TMAX*DIM f
  unsigned* ctr = (unsigned*)(zq_s + (size_t)10 * TMAX * DIM); // 32 x NCTR*CSTR u32
  unsigned* flag = ctr + (size_t)30 * NCTR * CSTR;         // epoch flag (zeroed by prep)
  float* blockmax_s = (float*)(ctr + (size_t)32 * NCTR * CSTR); // 10 x NRB*TMAX f (15 MB)

  prep_kernel<<<512, 256, 0, stream>>>(z, residual, out, rdown_s, ctr, out_size);
  fused_kernel<<<GRID, 256, 0, stream>>>(cb, rdown_s, blockmax_s, zq_s,
                                         residual, out, ctr, flag);
}

// Round 11
// 415.682 us; speedup vs baseline: 1.3225x; 1.0323x over previous
//
#include <hip/hip_runtime.h>
#include <stdint.h>

#define KCB 196560   // codebook rows
#define DIM 24       // embed dim
#define BB  2        // batch
#define ZEL 12288    // B*D*16*16
#define NRB 768      // row-blocks (768*256 = 196608 >= 196560)
#define RBS 256      // rows per score block
#define GRID 768     // persistent blocks; each owns one 256-row codebook slice in regs
#define NFIN 48      // update blocks (one (b,d) plane each)
#define TMAX 512     // max tokens per scale
#define SLOTS_PER_BAR 768
#define SLOT_STRIDE 4   // u32 stride (16 B) between slots: <=4 arrival stores per line

typedef __attribute__((ext_vector_type(8)))  __bf16 bf16x8;
typedef __attribute__((ext_vector_type(16))) float  f32x16;

__device__ const int TS_d[10] = {1, 2, 3, 4, 5, 6, 8, 10, 13, 16};

__device__ __forceinline__ unsigned long long pack_key(float sim, int idx) {
  unsigned u = __float_as_uint(sim);
  u = (u & 0x80000000u) ? ~u : (u | 0x80000000u);       // order-preserving float->u32
  return ((unsigned long long)u << 32) | (unsigned)(~(unsigned)idx); // smaller idx wins ties
}

// ---------- agent-scope (coherence-point) accessors ----------
__device__ __forceinline__ void st_agent(float* p, float v) {
  __hip_atomic_store((unsigned*)p, __float_as_uint(v),
                     __ATOMIC_RELAXED, __HIP_MEMORY_SCOPE_AGENT);
}

// ---------- store-slot barrier: arrive = ONE agent store (no RMW anywhere) ----------
// Ordering (rounds 6-9 proven): __syncthreads() drains vmcnt so all prior agent
// stores are acked at the coherence point BEFORE the slot store issues.
__device__ __forceinline__ void slot_arrive(unsigned* slots) {
  __syncthreads();
  if (threadIdx.x == 0)
    __hip_atomic_store(&slots[blockIdx.x * SLOT_STRIDE], 1u,
                       __ATOMIC_RELAXED, __HIP_MEMORY_SCOPE_AGENT);
}
template<int SLP>
__device__ __forceinline__ void slot_wait(unsigned* slots, int NB) {
  if (threadIdx.x < 64) {
    while (true) {
      unsigned s = 0;
      for (int k = threadIdx.x; k < NB; k += 64)
        s += __hip_atomic_load(&slots[k * SLOT_STRIDE],
                               __ATOMIC_RELAXED, __HIP_MEMORY_SCOPE_AGENT);
#pragma unroll
      for (int d = 32; d; d >>= 1) s += __shfl_xor(s, d);
      if (s >= (unsigned)NB) break;
      __builtin_amdgcn_s_sleep(SLP);          // literal constant (template param)
    }
  }
  __syncthreads();
  asm volatile("" ::: "memory");      // block compiler hoisting of data loads above wait
}

// ---------- split-bf16 conversion helpers (bit-identical to rounds 1-9) ----------
__device__ __forceinline__ void load8(const float* p, float* xs) {
  float4 a = *(const float4*)p;
  float4 b = *(const float4*)(p + 4);
  xs[0]=a.x; xs[1]=a.y; xs[2]=a.z; xs[3]=a.w;
  xs[4]=b.x; xs[5]=b.y; xs[6]=b.z; xs[7]=b.w;
}
__device__ __forceinline__ void cvt_hi_lo(const float* xs, uint4& hw, uint4& lw) {
  unsigned h[8], l[8];
#pragma unroll
  for (int j = 0; j < 8; ++j) {
    unsigned b = __float_as_uint(xs[j]);
    h[j] = b >> 16;
    float hif = __uint_as_float(b & 0xffff0000u);
    l[j] = __float_as_uint(xs[j] - hif) >> 16;   // exact in fp32
  }
  hw = make_uint4(h[0] | (h[1] << 16), h[2] | (h[3] << 16),
                  h[4] | (h[5] << 16), h[6] | (h[7] << 16));
  lw = make_uint4(l[0] | (l[1] << 16), l[2] | (l[3] << 16),
                  l[4] | (l[5] << 16), l[6] | (l[7] << 16));
}

// ---------- prep: zero out + slots, residual=z, t=1 downsample ----------
__global__ __launch_bounds__(256) void prep_kernel(const float* __restrict__ z,
    float* __restrict__ residual, float* __restrict__ out, float* __restrict__ rdown0,
    unsigned* __restrict__ slots, int outTotal) {
  __shared__ float plane[256];
  int tid = threadIdx.x;
  int e = blockIdx.x * 256 + tid;
  if (e < outTotal) out[e] = 0.0f;
  if (e < 30 * SLOTS_PER_BAR * SLOT_STRIDE) slots[e] = 0u;
  if (blockIdx.x < 48) {                       // 48 blocks = 48 (b,d) planes
    float v = z[e];
    residual[e] = v;
    plane[tid] = v;
    __syncthreads();
    if (tid == 0) {                            // t=1: single token per plane
      float inv_scale = 16.0f;
      float ks = inv_scale;
      float sf_h = 0.5f * inv_scale - 0.5f;
      float sf_w = 0.5f * inv_scale - 0.5f;
      float wh[16], ww[16];
      float sh = 0.f, sw = 0.f;
#pragma unroll
      for (int i = 0; i < 16; ++i) {
        float vh = fmaxf(0.f, 1.f - fabsf(sf_h - (float)i) / ks);
        wh[i] = vh; sh += vh;
        float vw = fmaxf(0.f, 1.f - fabsf(sf_w - (float)i) / ks);
        ww[i] = vw; sw += vw;
      }
#pragma unroll
      for (int i = 0; i < 16; ++i) { wh[i] /= sh; ww[i] /= sw; }
      float acc = 0.f;
      for (int ih = 0; ih < 16; ++ih) {
        float ra = 0.f;
#pragma unroll
        for (int iw = 0; iw < 16; ++iw) ra = fmaf(ww[iw], plane[ih * 16 + iw], ra);
        acc = fmaf(wh[ih], ra, acc);
      }
      int b = blockIdx.x / DIM, d = blockIdx.x - (blockIdx.x / DIM) * DIM;
      rdown0[b * DIM + d] = acc;               // normal store; boundary flush -> fresh
    }
  }
}

// ---------- finalize one token (one wave): prune + exact rescan + zq ----------
__device__ __forceinline__ void finalize_token(int tok, const float* __restrict__ cb,
    const float* __restrict__ rdown, const float* __restrict__ bm,
    float* __restrict__ zq, float* __restrict__ out, int idxBase) {
  int lane = threadIdx.x & 63;
  float x = (lane < DIM) ? rdown[tok * DIM + lane] : 0.f;   // cached (fresh this scale)
  float av[DIM];
#pragma unroll
  for (int k = 0; k < DIM; ++k)
    av[k] = __uint_as_float(__builtin_amdgcn_readlane(__float_as_uint(x), k));
  float ss = 0.f;
#pragma unroll
  for (int k = 0; k < DIM; ++k) ss = fmaf(av[k], av[k], ss);
  // eps = 1e-3*|a| >= 5x split-bf16 error bound: true argmax block provably kept
  float eps = 1e-3f * sqrtf(ss) + 1e-30f;

  float bv[12];
#pragma unroll
  for (int i = 0; i < 12; ++i)
    bv[i] = bm[(size_t)(lane + 64 * i) * TMAX + tok];        // cached, virgin this scale
  float M = bv[0];
#pragma unroll
  for (int i = 1; i < 12; ++i) M = fmaxf(M, bv[i]);
#pragma unroll
  for (int d = 32; d; d >>= 1) M = fmaxf(M, __shfl_xor(M, d));
  float thr = M - eps;

  unsigned long long bk = 0ull;
#pragma unroll
  for (int i = 0; i < 12; ++i) {
    unsigned long long mask = __ballot(bv[i] >= thr);
    while (mask) {                              // wave-uniform, expected ~1 iter total
      int l = __ffsll((unsigned long long)mask) - 1;
      mask &= mask - 1;
      int rowb = (l + 64 * i) * RBS;
      for (int r8 = 0; r8 < 4; ++r8) {          // RBS=256 -> 4 x 64 rows
        int row = rowb + r8 * 64 + lane;
        if (row < KCB) {
          const float* cv = cb + (size_t)row * DIM;
          float acc = 0.f;
#pragma unroll
          for (int k = 0; k < DIM; ++k) acc = fmaf(av[k], cv[k], acc);  // exact chain
          unsigned long long key = pack_key(acc, row);
          if (key > bk) bk = key;               // rows ascend per lane -> lowest idx kept
        }
      }
    }
  }
#pragma unroll
  for (int d = 32; d; d >>= 1) {
    unsigned long long o = __shfl_xor(bk, d);
    if (o > bk) bk = o;
  }
  int idx = (int)(~(unsigned)bk);
  const float* cv = cb + (long long)idx * DIM;
  float xv = (lane < DIM) ? cv[lane] : 0.f;
  float v[DIM];
#pragma unroll
  for (int k = 0; k < DIM; ++k)
    v[k] = __uint_as_float(__builtin_amdgcn_readlane(__float_as_uint(xv), k));
  float s2 = 0.f;
#pragma unroll
  for (int k = 0; k < DIM; ++k) s2 = fmaf(v[k], v[k], s2);
  float nrm = sqrtf(s2);
  if (lane < DIM) st_agent(&zq[tok * DIM + lane], xv / nrm);  // cross-block producer
  if (lane == 0) out[idxBase + tok] = (float)idx;
}

// ---------- update plane: upsample, z_hat/residual, next-scale downsample ----------
__device__ __forceinline__ void update_plane_rt(int tsz, int tnext,
    const float* __restrict__ zq, float* residual, float* __restrict__ out,
    float* rdown_next, float* ldsZ, float* plane) {
  int N = tsz * tsz;
  int tid = threadIdx.x;
  int p = blockIdx.x;
  int b = p / DIM, d = p - b * DIM;
  for (int sp = tid; sp < N; sp += 256) ldsZ[sp] = zq[(b * N + sp) * DIM + d];  // cached, virgin
  __syncthreads();
  int e = p * 256 + tid;
  int w = e & 15, h = (e >> 4) & 15;
  float inv_scale = (float)tsz / 16.0f;
  float sf_h = ((float)h + 0.5f) * inv_scale - 0.5f;
  float sf_w = ((float)w + 0.5f) * inv_scale - 0.5f;
  float wh[16], ww[16];
  float sh = 0.f, sw = 0.f;
  for (int j = 0; j < tsz; ++j) {
    float vh = fmaxf(0.f, 1.f - fabsf(sf_h - (float)j));
    wh[j] = vh; sh += vh;
    float vw = fmaxf(0.f, 1.f - fabsf(sf_w - (float)j));
    ww[j] = vw; sw += vw;
  }
  for (int j = 0; j < tsz; ++j) { wh[j] /= sh; ww[j] /= sw; }
  float acc = 0.f;
  for (int thh = 0; thh < tsz; ++thh) {
    float ra = 0.f;
    for (int tw = 0; tw < tsz; ++tw) ra = fmaf(ww[tw], ldsZ[thh * tsz + tw], ra);
    acc = fmaf(wh[thh], ra, acc);
  }
  out[e] += acc;                               // block-private lines: cached rd/wr
  float rn = residual[e] - acc;
  residual[e] = rn;

  if (tnext > 0) {                             // next-scale downsample, in-LDS
    plane[tid] = rn;
    __syncthreads();
    int n2 = tnext * tnext;
    for (int sp = tid; sp < n2; sp += 256) {
      int oh = sp / tnext, ow = sp - oh * tnext;
      float inv2 = 16.0f / (float)tnext;
      float ks = inv2;
      float s_h = ((float)oh + 0.5f) * inv2 - 0.5f;
      float s_w = ((float)ow + 0.5f) * inv2 - 0.5f;
      float wh2[16], ww2[16];
      float sh2 = 0.f, sw2 = 0.f;
      for (int i = 0; i < 16; ++i) {
        float vh = fmaxf(0.f, 1.f - fabsf(s_h - (float)i) / ks);
        wh2[i] = vh; sh2 += vh;
        float vw = fmaxf(0.f, 1.f - fabsf(s_w - (float)i) / ks);
        ww2[i] = vw; sw2 += vw;
      }
      for (int i = 0; i < 16; ++i) { wh2[i] /= sh2; ww2[i] /= sw2; }
      float acc2 = 0.f;
      for (int ih = 0; ih < 16; ++ih) {
        float ra = 0.f;
        for (int iw = 0; iw < 16; ++iw) ra = fmaf(ww2[iw], plane[ih * 16 + iw], ra);
        acc2 = fmaf(wh2[ih], ra, acc2);
      }
      st_agent(&rdown_next[(b * n2 + sp) * DIM + d], acc2);  // cross-block producer
    }
  }
}

// ---------- single persistent kernel: codebook fragments live in REGISTERS ----------
__global__ __launch_bounds__(256, 3) void fused_kernel(
    const float* __restrict__ cb,
    float* rdown_s, float* blockmax_s, float* zq_s,
    float* residual, float* out, unsigned* slots) {
  __shared__ __align__(16) ushort th_lds[TMAX * DIM];   // 24 KB token hi (whole scale)
  __shared__ __align__(16) ushort tl_lds[TMAX * DIM];   // 24 KB token lo
  __shared__ float lmax[4][4][32];                      // 2 KB
  __shared__ float ldsZ[256];
  __shared__ float plane[256];

  const int tid = threadIdx.x, lane = tid & 63, wv = tid >> 6;
  const int col = lane & 31, g = lane >> 5;
  const int bid = blockIdx.x;
  const uint4 z4 = make_uint4(0, 0, 0, 0);

  // ---- codebook fragments -> registers, ONCE (cached fp32 loads, hi/lo split) ----
  bf16x8 ah[2][2], al[2][2];   // [rt][khalf]
  int limit_rt[2];
#pragma unroll
  for (int rt = 0; rt < 2; ++rt) {
    int tilebase = bid * RBS + wv * 64 + rt * 32;
    limit_rt[rt] = KCB - tilebase;             // may be <=0 for the tail waves
    int row = tilebase + col;
    bool rv = (tilebase < KCB) && (row < KCB);
    uint4 h0 = z4, l0 = z4, h1 = z4, l1 = z4;
    if (rv) { float xs[8]; load8(cb + (size_t)row * DIM + g * 8, xs); cvt_hi_lo(xs, h0, l0); }
    if (rv && g == 0) { float xs[8]; load8(cb + (size_t)row * DIM + 16, xs); cvt_hi_lo(xs, h1, l1); }
    ah[rt][0] = __builtin_bit_cast(bf16x8, h0);
    ah[rt][1] = __builtin_bit_cast(bf16x8, h1);
    al[rt][0] = __builtin_bit_cast(bf16x8, l0);
    al[rt][1] = __builtin_bit_cast(bf16x8, l1);
  }
  const f32x16 fzero = {};

  int prefix = 0;
  for (int s = 0; s < 10; ++s) {
    const int t = TS_d[s];
    const int n = t * t, T = BB * n;
    const int ntb = (T + 127) >> 7;
    const int NFB = (T >= 96) ? 192 : 48;      // finalize block count
    float* rdown = rdown_s + (size_t)s * TMAX * DIM;
    float* bm    = blockmax_s + (size_t)s * NRB * TMAX;
    float* zq    = zq_s + (size_t)s * TMAX * DIM;
    unsigned* sA = slots + (size_t)(3 * s + 0) * SLOTS_PER_BAR * SLOT_STRIDE;
    unsigned* sB = slots + (size_t)(3 * s + 1) * SLOTS_PER_BAR * SLOT_STRIDE;
    unsigned* sC = slots + (size_t)(3 * s + 2) * SLOTS_PER_BAR * SLOT_STRIDE;

    // ---- stage whole scale's tokens -> LDS packed (CACHED float4 loads) ----
    __syncthreads();
    for (int i4 = tid; i4 < (T * DIM) >> 2; i4 += 256) {
      float4 v4 = *((const float4*)rdown + i4);
      float xs[4] = {v4.x, v4.y, v4.z, v4.w};
      unsigned h[4], l[4];
#pragma unroll
      for (int k = 0; k < 4; ++k) {
        unsigned bits = __float_as_uint(xs[k]);
        h[k] = bits >> 16;
        float hif = __uint_as_float(bits & 0xffff0000u);
        l[k] = __float_as_uint(xs[k] - hif) >> 16;   // exact in fp32
      }
      *(uint2*)&th_lds[i4 * 4] = make_uint2(h[0] | (h[1] << 16), h[2] | (h[3] << 16));
      *(uint2*)&tl_lds[i4 * 4] = make_uint2(l[0] | (l[1] << 16), l[2] | (l[3] << 16));
    }
    __syncthreads();

    // ---- score all token tiles against this block's register-resident codebook ----
    for (int tb = 0; tb < ntb; ++tb) {
      int tbase = tb * 128;
      int nrem = T - tbase;
      int ntt = min(4, (nrem + 31) >> 5);
      bf16x8 bh[4][2], bl[4][2];
#pragma unroll
      for (int tt = 0; tt < 4; ++tt) {
        int lt = tbase + tt * 32 + col;
        bool tv = (tt < ntt) && (lt < T);
        uint4 h0 = tv ? *(const uint4*)&th_lds[lt * DIM + g * 8] : z4;
        uint4 h1 = (tv && g == 0) ? *(const uint4*)&th_lds[lt * DIM + 16] : z4;
        uint4 l0 = tv ? *(const uint4*)&tl_lds[lt * DIM + g * 8] : z4;
        uint4 l1 = (tv && g == 0) ? *(const uint4*)&tl_lds[lt * DIM + 16] : z4;
        bh[tt][0] = __builtin_bit_cast(bf16x8, h0);
        bh[tt][1] = __builtin_bit_cast(bf16x8, h1);
        bl[tt][0] = __builtin_bit_cast(bf16x8, l0);
        bl[tt][1] = __builtin_bit_cast(bf16x8, l1);
      }
      float runmax[4] = {-3.402823466e38f, -3.402823466e38f,
                         -3.402823466e38f, -3.402823466e38f};
#pragma unroll
      for (int rt = 0; rt < 2; ++rt) {
        int limit = limit_rt[rt];
        if (limit <= 0) continue;              // wave-uniform
        bool full = limit >= 32;
#pragma unroll
        for (int tt = 0; tt < 4; ++tt) {
          if (tt >= ntt) continue;
          f32x16 acc = __builtin_amdgcn_mfma_f32_32x32x16_bf16(ah[rt][0], bh[tt][0], fzero, 0, 0, 0);
          acc = __builtin_amdgcn_mfma_f32_32x32x16_bf16(ah[rt][1], bh[tt][1], acc, 0, 0, 0);
          acc = __builtin_amdgcn_mfma_f32_32x32x16_bf16(al[rt][0], bh[tt][0], acc, 0, 0, 0);
          acc = __builtin_amdgcn_mfma_f32_32x32x16_bf16(al[rt][1], bh[tt][1], acc, 0, 0, 0);
          acc = __builtin_amdgcn_mfma_f32_32x32x16_bf16(ah[rt][0], bl[tt][0], acc, 0, 0, 0);
          acc = __builtin_amdgcn_mfma_f32_32x32x16_bf16(ah[rt][1], bl[tt][1], acc, 0, 0, 0);
          float m;
          if (full) {
            float m01 = fmaxf(acc[0], acc[1]),  m23 = fmaxf(acc[2], acc[3]);
            float m45 = fmaxf(acc[4], acc[5]),  m67 = fmaxf(acc[6], acc[7]);
            float m89 = fmaxf(acc[8], acc[9]),  mab = fmaxf(acc[10], acc[11]);
            float mcd = fmaxf(acc[12], acc[13]), mef = fmaxf(acc[14], acc[15]);
            m = fmaxf(fmaxf(fmaxf(m01, m23), fmaxf(m45, m67)),
                      fmaxf(fmaxf(m89, mab), fmaxf(mcd, mef)));
          } else {
            m = -3.402823466e38f;              // mask rows >= KCB
#pragma unroll
            for (int r = 0; r < 16; ++r) {
              int rowid = (r & 3) + 8 * (r >> 2) + 4 * g;
              if (rowid < limit) m = fmaxf(m, acc[r]);
            }
          }
          runmax[tt] = fmaxf(runmax[tt], m);
        }
      }
#pragma unroll
      for (int tt = 0; tt < 4; ++tt) {
        float v = fmaxf(runmax[tt], __shfl_xor(runmax[tt], 32));
        if (lane < 32) lmax[wv][tt][col] = v;
      }
      __syncthreads();
      if (tid < 128) {
        int tt = tid >> 5, c = tid & 31;
        if (tt < ntt) {
          float m = fmaxf(fmaxf(lmax[0][tt][c], lmax[1][tt][c]),
                          fmaxf(lmax[2][tt][c], lmax[3][tt][c]));
          int token = tbase + tt * 32 + c;
          if (token < T)
            st_agent(&bm[(size_t)bid * TMAX + token], m);   // COALESCED [rb][tok] write
        }
      }
      __syncthreads();                         // lmax WAR before next tile
    }
    slot_arrive(sA);

    if (bid < NFB) {
      // phase B: finalize over contiguous token chunks (NFB blocks)
      slot_wait<1>(sA, GRID);
      int chunk = (T + NFB - 1) / NFB;
      int tbeg = bid * chunk, tend = min(T, tbeg + chunk);
      for (int tok = tbeg + wv; tok < tend; tok += 4)
        finalize_token(tok, cb, rdown, bm, zq, out, ZEL + BB * prefix);
      slot_arrive(sB);
    }
    if (bid < NFIN) {
      slot_wait<1>(sB, NFB);
      // phase C: update plane bid (+ next-scale downsample into rdown_s[s+1])
      update_plane_rt(t, (s < 9) ? TS_d[s + 1] : 0, zq, residual, out,
                      rdown_s + (size_t)(s + 1) * TMAX * DIM, ldsZ, plane);
      if (s < 9) slot_arrive(sC);
    }
    if (s < 9) slot_wait<2>(sC, NFIN);         // direct 48-slot poll; no aggregator hop
    prefix += n;
  }
}

// ---------- host: 2 dispatches total ----------
extern "C" void kernel_launch(void* const* d_in, const int* in_sizes, int n_in,
                              void* d_out, int out_size, void* d_ws, size_t ws_size,
                              hipStream_t stream) {
  const float* z  = (const float*)d_in[0];
  const float* cb = (const float*)d_in[1];
  float* out = (float*)d_out;
  float* residual = (float*)d_ws;                          // 12288 f
  float* rdown_s = residual + ZEL;                         // 11 x TMAX*DIM f
  float* zq_s = rdown_s + (size_t)11 * TMAX * DIM;         // 10 x TMAX*DIM f
  unsigned* slots = (unsigned*)(zq_s + (size_t)10 * TMAX * DIM); // 30 x 768 x 4 u32
  float* blockmax_s = (float*)(slots + (size_t)30 * SLOTS_PER_BAR * SLOT_STRIDE); // 10 x NRB*TMAX f

  prep_kernel<<<512, 256, 0, stream>>>(z, residual, out, rdown_s, slots, out_size);
  fused_kernel<<<GRID, 256, 0, stream>>>(cb, rdown_s, blockmax_s, zq_s,
                                         residual, out, slots);
}